// Round 1
// baseline (414.497 us; speedup 1.0000x reference)
//
#include <hip/hip_runtime.h>

typedef unsigned short u16;

#define NQ 14
#define NSTATE (1 << NQ)   // 16384
#define DEPTH 8
#define TPB 512

// ---------- host-side constants passed by value ----------
struct PassK {
  u16 pivotmask;   // pivot bit positions (rep bits forced 0 here)
  u16 srow[5];     // rows of L for base-parity (sign of sin)
  u16 xm[32];      // coset offset masks (XOR combos of pair masks)
};  // 76 bytes

struct SimConsts {
  PassK pass[7][3];   // layers 1..7 x {wires 0-4, 5-9, 10-13}
  u16 zrow[14];       // rows of L_8 for <Z_w> sign
};  // 1624 bytes

// ---------- device ----------
__device__ __forceinline__ unsigned phi_swz(unsigned p) {
  // involution: XOR bits 5..8 into bits 1..4 to break bank patterns
  return p ^ (((p >> 5) & 15u) << 1);
}
__device__ __forceinline__ float2 cmul(float2 a, float2 b) {
  return make_float2(a.x * b.x - a.y * b.y, a.x * b.y + a.y * b.x);
}

template <int NW_>
__device__ __forceinline__ void ry_group(float2* st, const PassK& P,
                                         const float* th, int wbase, int grp) {
  constexpr int NE = 1 << NW_;
  // spread grp bits over non-pivot positions -> coset representative
  unsigned rep = 0;
  {
    unsigned tb = (unsigned)grp;
    #pragma unroll
    for (int j = 0; j < NQ; ++j) {
      if (!((P.pivotmask >> j) & 1)) { rep |= (tb & 1u) << j; tb >>= 1; }
    }
  }
  float c[NW_], sa[NW_];
  #pragma unroll
  for (int i = 0; i < NW_; ++i) {
    float ss, cc;
    sincosf(0.5f * th[wbase + i], &ss, &cc);
    c[i] = cc;
    // base parity: does a[e_i=0] hold logical |1>? then flip sin sign
    sa[i] = (__popc((unsigned)P.srow[i] & rep) & 1) ? -ss : ss;
  }
  unsigned addr[NE];
  #pragma unroll
  for (int e = 0; e < NE; ++e) addr[e] = phi_swz(rep ^ (unsigned)P.xm[e]);
  float2 a[NE];
  #pragma unroll
  for (int e = 0; e < NE; ++e) a[e] = st[addr[e]];
  #pragma unroll
  for (int i = 0; i < NW_; ++i) {
    #pragma unroll
    for (int e = 0; e < NE; ++e) {
      if (!(e & (1 << i))) {
        float2 x = a[e], y = a[e | (1 << i)];
        float ci = c[i], si = sa[i];
        a[e]            = make_float2(ci * x.x - si * y.x, ci * x.y - si * y.y);
        a[e | (1 << i)] = make_float2(si * x.x + ci * y.x, si * x.y + ci * y.y);
      }
    }
  }
  #pragma unroll
  for (int e = 0; e < NE; ++e) st[addr[e]] = a[e];
}

__global__ __launch_bounds__(TPB, 1) void qsim_kernel(
    const float* __restrict__ inp, const float* __restrict__ theta,
    float* __restrict__ out, SimConsts C) {
  __shared__ float2 st[NSTATE];   // 128 KiB
  const int s = blockIdx.x;
  const int t = threadIdx.x;

  // ---- init: product state after RX(inp) then RY(theta layer 0)
  // per-wire vector: alpha=(ct*cx, st*sx), beta=(st*cx, -ct*sx)
  float2 rhi = make_float2(1.f, 0.f);
  #pragma unroll
  for (int b = 0; b < 9; ++b) {          // p bit b <- t bit b, wire 13-b
    const int w = 13 - b;
    float sx, cx; sincosf(0.5f * inp[s * NQ + w], &sx, &cx);
    float stt, ctt; sincosf(0.5f * theta[w], &stt, &ctt);
    float2 al = make_float2(ctt * cx, stt * sx);
    float2 be = make_float2(stt * cx, -ctt * sx);
    float2 f = ((t >> b) & 1) ? be : al;
    rhi = cmul(rhi, f);
  }
  float2 a[32];
  a[0] = rhi;
  #pragma unroll
  for (int k = 0; k < 5; ++k) {          // e bit k <-> p bit 9+k <-> wire 4-k
    const int w = 4 - k;
    float sx, cx; sincosf(0.5f * inp[s * NQ + w], &sx, &cx);
    float stt, ctt; sincosf(0.5f * theta[w], &stt, &ctt);
    float2 al = make_float2(ctt * cx, stt * sx);
    float2 be = make_float2(stt * cx, -ctt * sx);
    const int sz = 1 << k;
    #pragma unroll
    for (int j = 0; j < 16; ++j) {
      if (j < sz) {
        float2 v = a[j];
        a[j]      = cmul(v, al);
        a[j + sz] = cmul(v, be);
      }
    }
  }
  #pragma unroll
  for (int e = 0; e < 32; ++e)
    st[phi_swz(((unsigned)e << 9) | (unsigned)t)] = a[e];
  __syncthreads();

  // ---- layers 1..7: RY only (rings absorbed into the L/K linear maps)
  #pragma unroll 1
  for (int d = 1; d <= 7; ++d) {
    const float* th = theta + d * NQ;
    ry_group<5>(st, C.pass[d - 1][0], th, 0, t);
    __syncthreads();
    ry_group<5>(st, C.pass[d - 1][1], th, 5, t);
    __syncthreads();
    ry_group<4>(st, C.pass[d - 1][2], th, 10, t);          // disjoint cosets:
    ry_group<4>(st, C.pass[d - 1][2], th, 10, t + TPB);    // no sync needed between
    __syncthreads();
  }

  // ---- measurement: <Z_w> with sign = parity(row_w(L_8) & p)
  float acc[NQ];
  #pragma unroll
  for (int w = 0; w < NQ; ++w) acc[w] = 0.f;
  #pragma unroll
  for (int e = 0; e < 32; ++e) {
    unsigned p = ((unsigned)e << 9) | (unsigned)t;
    float2 v = st[phi_swz(p)];
    float pv = v.x * v.x + v.y * v.y;
    #pragma unroll
    for (int w = 0; w < NQ; ++w)
      acc[w] += (__popc((unsigned)C.zrow[w] & p) & 1) ? -pv : pv;
  }
  #pragma unroll
  for (int w = 0; w < NQ; ++w) {
    #pragma unroll
    for (int off = 32; off > 0; off >>= 1)
      acc[w] += __shfl_xor(acc[w], off, 64);
  }
  __syncthreads();                 // state no longer needed -> reuse as scratch
  float* scratch = (float*)st;
  const int lane = t & 63, wid = t >> 6;
  if (lane == 0) {
    #pragma unroll
    for (int w = 0; w < NQ; ++w) scratch[wid * NQ + w] = acc[w];
  }
  __syncthreads();
  if (t < NQ) {
    float tot = 0.f;
    #pragma unroll
    for (int k = 0; k < 8; ++k) tot += scratch[k * NQ + t];
    out[s * NQ + t] = tot;
  }
}

// ---------- host: GF(2) linear algebra for the CNOT-ring permutation ----------
// bit j of index (LSB=0) corresponds to wire 13-j.
// Ring = CNOT(0,1)..CNOT(12,13),CNOT(13,0) acting on bits:
// y_j = x_j ^ ... ^ x_13 (j<=12); y_13 = x_0 ^ ... ^ x_12
static inline unsigned ffwd(unsigned x) {
  unsigned t = x;
  t ^= t >> 1; t ^= t >> 2; t ^= t >> 4; t ^= t >> 8;
  unsigned y = t & 0x1FFFu;
  y |= (((t >> 13) ^ t) & 1u) << 13;
  return y;
}
static inline unsigned finv(unsigned y) {
  unsigned x = 0;
  for (int j = 0; j <= 11; ++j) x |= (((y >> j) ^ (y >> (j + 1))) & 1u) << j;
  x |= (((y >> 12) ^ (y >> 13) ^ y) & 1u) << 12;
  x |= (((y >> 13) ^ y) & 1u) << 13;
  return x;
}

extern "C" void kernel_launch(void* const* d_in, const int* in_sizes, int n_in,
                              void* d_out, int out_size, void* d_ws, size_t ws_size,
                              hipStream_t stream) {
  const float* inp = (const float*)d_in[0];
  const float* theta = (const float*)d_in[1];
  float* out = (float*)d_out;
  const int batch = in_sizes[0] / NQ;

  SimConsts C;
  u16 Lc[NQ], Kc[NQ];   // columns of L = F^d and K = L^-1
  for (int j = 0; j < NQ; ++j) { Lc[j] = (u16)(1u << j); Kc[j] = (u16)(1u << j); }
  for (int d = 1; d <= 8; ++d) {
    u16 nL[NQ], nK[NQ];
    for (int j = 0; j < NQ; ++j) nL[j] = (u16)ffwd((unsigned)Lc[j]);
    for (int j = 0; j < NQ; ++j) {
      unsigned fj = finv(1u << j);
      unsigned v = 0;
      for (int b = 0; b < NQ; ++b) if ((fj >> b) & 1u) v ^= Kc[b];
      nK[j] = (u16)v;
    }
    for (int j = 0; j < NQ; ++j) { Lc[j] = nL[j]; Kc[j] = nK[j]; }

    if (d <= 7) {
      for (int pg = 0; pg < 3; ++pg) {
        const int wbase = pg * 5;
        const int nw = (pg == 2) ? 4 : 5;
        PassK& P = C.pass[d - 1][pg];
        u16 mk[5] = {0, 0, 0, 0, 0};
        for (int i = 0; i < 5; ++i) P.srow[i] = 0;
        for (int i = 0; i < nw; ++i) {
          const int bit = 13 - (wbase + i);
          mk[i] = Kc[bit];                       // pair mask = column of K
          unsigned r = 0;                        // row of L at 'bit'
          for (int j = 0; j < NQ; ++j) r |= ((unsigned)(Lc[j] >> bit) & 1u) << j;
          P.srow[i] = (u16)r;
        }
        // echelon pivots (highest set bits) for coset-rep enumeration
        unsigned red[5]; int piv[5]; unsigned pm = 0;
        for (int i = 0; i < nw; ++i) {
          unsigned m = mk[i];
          for (int k2 = 0; k2 < i; ++k2)
            if ((m >> piv[k2]) & 1u) m ^= red[k2];
          int h = 31 - __builtin_clz(m);
          red[i] = m; piv[i] = h; pm |= 1u << h;
        }
        P.pivotmask = (u16)pm;
        const int ne = 1 << nw;
        for (int e = 0; e < 32; ++e) {
          unsigned v = 0;
          if (e < ne)
            for (int i = 0; i < nw; ++i)
              if ((e >> i) & 1) v ^= mk[i];
          P.xm[e] = (u16)v;
        }
      }
    } else {
      for (int w = 0; w < NQ; ++w) {
        const int bit = 13 - w;
        unsigned r = 0;
        for (int j = 0; j < NQ; ++j) r |= ((unsigned)(Lc[j] >> bit) & 1u) << j;
        C.zrow[w] = (u16)r;
      }
    }
  }

  qsim_kernel<<<batch, TPB, 0, stream>>>(inp, theta, out, C);
}

// Round 2
// 262.579 us; speedup vs baseline: 1.5786x; 1.5786x over previous
//
#include <hip/hip_runtime.h>

typedef unsigned short u16;
typedef float f2 __attribute__((ext_vector_type(2)));

#define NQ 14
#define NSTATE (1 << NQ)   // 16384
#define DEPTH 8
#define BATCH_NQ_MAX 0     // batch derived at runtime
#define TPB 512

// ---------- host-side constants passed by value ----------
struct PassK {
  u16 srow[5];     // rows of L: sign of sin per wire (parity with rep)
  u16 scol[10];    // spread columns: grp bit b -> unit vector at b-th non-pivot pos
  u16 xm[32];      // coset offset masks (XOR combos of pair masks)
};  // 94 bytes

struct SimConsts {
  PassK pass[7][3];   // layers 1..7 x {wires 0-4, 5-9, 10-13}
  u16 zrow[14];       // rows of L_8 for <Z_w> sign
};  // ~2002 bytes

// ---------- device ----------
__device__ __forceinline__ f2 cmulv(f2 a, f2 b) {
  f2 r;
  r.x = a.x * b.x - a.y * b.y;
  r.y = a.x * b.y + a.y * b.x;
  return r;
}

template <int NW_, bool USE_WS>
__device__ __forceinline__ void ry_group(f2* st, const PassK& P,
                                         const float* th, const float2* ttd,
                                         int wbase, unsigned grp) {
  constexpr int NE = 1 << NW_;
  constexpr int NB = 14 - NW_;
  // coset representative: XOR of spread columns for set grp bits (linear)
  unsigned rep = 0;
  #pragma unroll
  for (int b = 0; b < NB; ++b)
    rep ^= ((grp >> b) & 1u) ? (unsigned)P.scol[b] : 0u;

  float c[NW_], sa[NW_];
  #pragma unroll
  for (int i = 0; i < NW_; ++i) {
    float cc, ss;
    if constexpr (USE_WS) {
      float2 tv = ttd[wbase + i];    // uniform -> s_load
      cc = tv.x; ss = tv.y;
    } else {
      __sincosf(0.5f * th[wbase + i], &ss, &cc);
    }
    c[i] = cc;
    sa[i] = (__popc((unsigned)P.srow[i] & rep) & 1) ? -ss : ss;
  }

  unsigned rep8 = rep << 3;
  unsigned ad[NE];
  #pragma unroll
  for (int e = 0; e < NE; ++e)
    ad[e] = rep8 ^ (((unsigned)P.xm[e]) << 3);   // xm<<3 folds to SALU (uniform)

  f2 a[NE];
  #pragma unroll
  for (int e = 0; e < NE; ++e) a[e] = *(const f2*)((const char*)st + ad[e]);

  #pragma unroll
  for (int i = 0; i < NW_; ++i) {
    const float ci = c[i], si = sa[i];
    #pragma unroll
    for (int e = 0; e < NE; ++e) {
      if (!(e & (1 << i))) {
        f2 xe = a[e], ye = a[e | (1 << i)];
        a[e]            = ci * xe - si * ye;   // v_pk_fma candidates
        a[e | (1 << i)] = si * xe + ci * ye;
      }
    }
  }
  #pragma unroll
  for (int e = 0; e < NE; ++e) *(f2*)((char*)st + ad[e]) = a[e];
}

template <bool USE_WS>
__global__ __launch_bounds__(TPB, 1) void qsim_kernel(
    const float* __restrict__ inp, const float* __restrict__ theta,
    float* __restrict__ out, const float2* __restrict__ tt,
    const float4* __restrict__ albe, int use_albe, SimConsts C) {
  __shared__ f2 st[NSTATE];   // 128 KiB
  const int s = blockIdx.x;
  const int t = threadIdx.x;

  // ---- init: product state after RX(inp) then RY(theta layer 0)
  f2 A[NQ], B[NQ];
  if constexpr (USE_WS) {
    if (use_albe) {
      #pragma unroll
      for (int w = 0; w < NQ; ++w) {
        float4 v = albe[s * NQ + w];       // uniform -> s_load_dwordx4
        A[w].x = v.x; A[w].y = v.y;
        B[w].x = v.z; B[w].y = v.w;
      }
    } else {
      #pragma unroll
      for (int w = 0; w < NQ; ++w) {
        float sx, cx; __sincosf(0.5f * inp[s * NQ + w], &sx, &cx);
        float2 tv = tt[w];                 // layer-0 theta trig
        A[w].x = tv.x * cx; A[w].y = tv.y * sx;
        B[w].x = tv.y * cx; B[w].y = -tv.x * sx;
      }
    }
  } else {
    #pragma unroll
    for (int w = 0; w < NQ; ++w) {
      float sx, cx; __sincosf(0.5f * inp[s * NQ + w], &sx, &cx);
      float stt, ctt; __sincosf(0.5f * theta[w], &stt, &ctt);
      A[w].x = ctt * cx; A[w].y = stt * sx;
      B[w].x = stt * cx; B[w].y = -ctt * sx;
    }
  }

  f2 rhi; rhi.x = 1.f; rhi.y = 0.f;
  #pragma unroll
  for (int b = 0; b < 9; ++b) {            // p bit b <- t bit b, wire 13-b
    const int w = 13 - b;
    f2 f = ((t >> b) & 1) ? B[w] : A[w];
    rhi = cmulv(rhi, f);
  }
  f2 a[32];
  a[0] = rhi;
  #pragma unroll
  for (int k = 0; k < 5; ++k) {            // e bit k <-> p bit 9+k <-> wire 4-k
    const int w = 4 - k;
    const int sz = 1 << k;
    #pragma unroll
    for (int j = 0; j < 16; ++j) {
      if (j < sz) {
        f2 v = a[j];
        a[j]      = cmulv(v, A[w]);
        a[j + sz] = cmulv(v, B[w]);
      }
    }
  }
  #pragma unroll
  for (int e = 0; e < 32; ++e) st[(e << 9) | t] = a[e];
  __syncthreads();

  // ---- layers 1..7: RY only (CNOT rings absorbed into the L/K linear maps)
  #pragma unroll 1
  for (int d = 1; d <= 7; ++d) {
    const float* th = theta + d * NQ;
    const float2* ttd = USE_WS ? (tt + d * NQ) : nullptr;
    ry_group<5, USE_WS>(st, C.pass[d - 1][0], th, ttd, 0, (unsigned)t);
    __syncthreads();
    ry_group<5, USE_WS>(st, C.pass[d - 1][1], th, ttd, 5, (unsigned)t);
    __syncthreads();
    ry_group<4, USE_WS>(st, C.pass[d - 1][2], th, ttd, 10, (unsigned)t);
    ry_group<4, USE_WS>(st, C.pass[d - 1][2], th, ttd, 10, (unsigned)(t + TPB));
    __syncthreads();
  }

  // ---- measurement: <Z_w> via 5-bit Walsh-Hadamard over the e-axis
  float pv[32];
  #pragma unroll
  for (int e = 0; e < 32; ++e) {
    f2 v = st[(e << 9) | t];
    pv[e] = v.x * v.x + v.y * v.y;
  }
  __syncthreads();
  #pragma unroll
  for (int s5 = 0; s5 < 5; ++s5) {
    const int step = 1 << s5;
    #pragma unroll
    for (int e = 0; e < 32; ++e) {
      if (!(e & step)) {
        float x = pv[e], y = pv[e | step];
        pv[e] = x + y; pv[e | step] = x - y;
      }
    }
  }
  float* stf = (float*)st;
  #pragma unroll
  for (int e = 0; e < 32; ++e) stf[(e << 9) | t] = pv[e];   // [lam][t] layout
  __syncthreads();

  float acc[NQ];
  #pragma unroll
  for (int w = 0; w < NQ; ++w) {
    const unsigned zr = (unsigned)C.zrow[w];
    float v = stf[(zr & 0x3E00u) | (unsigned)t];   // WHT at frequency zr>>9
    acc[w] = (__popc(zr & (unsigned)t) & 1) ? -v : v;
  }
  #pragma unroll
  for (int w = 0; w < NQ; ++w) {
    #pragma unroll
    for (int off = 32; off > 0; off >>= 1)
      acc[w] += __shfl_xor(acc[w], off, 64);
  }
  __syncthreads();
  const int lane = t & 63, wid = t >> 6;
  if (lane == 0) {
    #pragma unroll
    for (int w = 0; w < NQ; ++w) stf[wid * NQ + w] = acc[w];
  }
  __syncthreads();
  if (t < NQ) {
    float tot = 0.f;
    #pragma unroll
    for (int k = 0; k < 8; ++k) tot += stf[k * NQ + t];
    out[s * NQ + t] = tot;
  }
}

// ---------- prep: precise trig tables into workspace ----------
__global__ void prep_kernel(const float* __restrict__ inp,
                            const float* __restrict__ theta,
                            float2* __restrict__ tt, float4* __restrict__ albe,
                            int nAlbe) {
  const int i = blockIdx.x * 256 + threadIdx.x;
  if (i < DEPTH * NQ) {
    float ss, cc; sincosf(0.5f * theta[i], &ss, &cc);
    tt[i] = make_float2(cc, ss);
  }
  if (albe != nullptr && i < nAlbe) {
    const int w = i % NQ;
    float sx, cx; sincosf(0.5f * inp[i], &sx, &cx);
    float stt, ctt; sincosf(0.5f * theta[w], &stt, &ctt);
    albe[i] = make_float4(ctt * cx, stt * sx, stt * cx, -ctt * sx);
  }
}

// ---------- host: GF(2) linear algebra for the CNOT-ring permutation ----------
static inline unsigned ffwd(unsigned x) {
  unsigned t = x;
  t ^= t >> 1; t ^= t >> 2; t ^= t >> 4; t ^= t >> 8;
  unsigned y = t & 0x1FFFu;
  y |= (((t >> 13) ^ t) & 1u) << 13;
  return y;
}
static inline unsigned finv(unsigned y) {
  unsigned x = 0;
  for (int j = 0; j <= 11; ++j) x |= (((y >> j) ^ (y >> (j + 1))) & 1u) << j;
  x |= (((y >> 12) ^ (y >> 13) ^ y) & 1u) << 12;
  x |= (((y >> 13) ^ y) & 1u) << 13;
  return x;
}

extern "C" void kernel_launch(void* const* d_in, const int* in_sizes, int n_in,
                              void* d_out, int out_size, void* d_ws, size_t ws_size,
                              hipStream_t stream) {
  const float* inp = (const float*)d_in[0];
  const float* theta = (const float*)d_in[1];
  float* out = (float*)d_out;
  const int batch = in_sizes[0] / NQ;

  SimConsts C;
  u16 Lc[NQ], Kc[NQ];   // columns of L = F^d and K = L^-1
  for (int j = 0; j < NQ; ++j) { Lc[j] = (u16)(1u << j); Kc[j] = (u16)(1u << j); }
  for (int d = 1; d <= 8; ++d) {
    u16 nL[NQ], nK[NQ];
    for (int j = 0; j < NQ; ++j) nL[j] = (u16)ffwd((unsigned)Lc[j]);
    for (int j = 0; j < NQ; ++j) {
      unsigned fj = finv(1u << j);
      unsigned v = 0;
      for (int b = 0; b < NQ; ++b) if ((fj >> b) & 1u) v ^= Kc[b];
      nK[j] = (u16)v;
    }
    for (int j = 0; j < NQ; ++j) { Lc[j] = nL[j]; Kc[j] = nK[j]; }

    if (d <= 7) {
      for (int pg = 0; pg < 3; ++pg) {
        const int wbase = pg * 5;
        const int nw = (pg == 2) ? 4 : 5;
        PassK& P = C.pass[d - 1][pg];
        u16 mk[5] = {0, 0, 0, 0, 0};
        for (int i = 0; i < 5; ++i) P.srow[i] = 0;
        for (int i = 0; i < nw; ++i) {
          const int bit = 13 - (wbase + i);
          mk[i] = Kc[bit];                       // pair mask = column of K
          unsigned r = 0;                        // row of L at 'bit'
          for (int j = 0; j < NQ; ++j) r |= ((unsigned)(Lc[j] >> bit) & 1u) << j;
          P.srow[i] = (u16)r;
        }
        // echelon pivots (highest set bits) for coset-rep enumeration
        unsigned red[5]; int piv[5]; unsigned pm = 0;
        for (int i = 0; i < nw; ++i) {
          unsigned m = mk[i];
          for (int k2 = 0; k2 < i; ++k2)
            if ((m >> piv[k2]) & 1u) m ^= red[k2];
          int h = 31 - __builtin_clz(m);
          red[i] = m; piv[i] = h; pm |= 1u << h;
        }
        // spread columns: ascending non-pivot unit vectors
        int b = 0;
        for (int j = 0; j < NQ; ++j)
          if (!((pm >> j) & 1u)) P.scol[b++] = (u16)(1u << j);
        for (; b < 10; ++b) P.scol[b] = 0;
        const int ne = 1 << nw;
        for (int e = 0; e < 32; ++e) {
          unsigned v = 0;
          if (e < ne)
            for (int i = 0; i < nw; ++i)
              if ((e >> i) & 1) v ^= mk[i];
          P.xm[e] = (u16)v;
        }
      }
    } else {
      for (int w = 0; w < NQ; ++w) {
        const int bit = 13 - w;
        unsigned r = 0;
        for (int j = 0; j < NQ; ++j) r |= ((unsigned)(Lc[j] >> bit) & 1u) << j;
        C.zrow[w] = (u16)r;
      }
    }
  }

  // workspace layout: [0,896) theta trig (float2), [1024, 1024+batch*NQ*16) albe (float4)
  const size_t needT = (size_t)(DEPTH * NQ) * sizeof(float2);
  const size_t needA = 1024 + (size_t)batch * NQ * sizeof(float4);
  const bool useT = ws_size >= 1024 && needT <= 1024;
  const bool useA = useT && ws_size >= needA;
  float2* tt = (float2*)d_ws;
  float4* albe = (float4*)((char*)d_ws + 1024);

  if (useT) {
    const int nAlbe = useA ? batch * NQ : 0;
    const int nwork = useA ? nAlbe : DEPTH * NQ;
    prep_kernel<<<(nwork + 255) / 256, 256, 0, stream>>>(
        inp, theta, tt, useA ? albe : nullptr, nAlbe);
    qsim_kernel<true><<<batch, TPB, 0, stream>>>(inp, theta, out, tt, albe,
                                                 useA ? 1 : 0, C);
  } else {
    qsim_kernel<false><<<batch, TPB, 0, stream>>>(inp, theta, out, nullptr,
                                                  nullptr, 0, C);
  }
}

// Round 3
// 243.846 us; speedup vs baseline: 1.6998x; 1.0768x over previous
//
#include <hip/hip_runtime.h>

typedef unsigned short u16;
typedef float f2 __attribute__((ext_vector_type(2)));

#define NQ 14
#define NSTATE (1 << NQ)   // 16384
#define DEPTH 8
#define TPB 512

// ---------- host-side constants passed by value ----------
struct PassK {
  u16 srow[5];     // rows of L: sign of sin per wire (parity with rep)
  u16 scol[10];    // complement basis: grp bit b -> scol[b] (conflict-free choice)
  u16 xm[32];      // coset offset masks (XOR combos of pair masks)
};

struct SimConsts {
  PassK pass[7][3];   // layers 1..7 x {wires 0-4, 5-9, 10-13}
  u16 zrow[14];       // rows of L_8 for <Z_w> sign
};

// ---------- device ----------
__device__ __forceinline__ f2 cmulv(f2 a, f2 b) {
  f2 r;
  r.x = a.x * b.x - a.y * b.y;
  r.y = a.x * b.y + a.y * b.x;
  return r;
}

template <int NW_, bool USE_WS>
__device__ __forceinline__ void ry_group(f2* st, const PassK& P,
                                         const float* th, const float2* ttd,
                                         int wbase, unsigned grp) {
  constexpr int NE = 1 << NW_;
  constexpr int NB = 14 - NW_;
  // coset representative: XOR of complement-basis columns for set grp bits
  unsigned rep = 0;
  #pragma unroll
  for (int b = 0; b < NB; ++b)
    rep ^= ((grp >> b) & 1u) ? (unsigned)P.scol[b] : 0u;

  float c[NW_], sa[NW_];
  #pragma unroll
  for (int i = 0; i < NW_; ++i) {
    float cc, ss;
    if constexpr (USE_WS) {
      float2 tv = ttd[wbase + i];    // uniform -> s_load
      cc = tv.x; ss = tv.y;
    } else {
      __sincosf(0.5f * th[wbase + i], &ss, &cc);
    }
    c[i] = cc;
    sa[i] = (__popc((unsigned)P.srow[i] & rep) & 1) ? -ss : ss;
  }

  unsigned rep8 = rep << 3;
  unsigned ad[NE];
  #pragma unroll
  for (int e = 0; e < NE; ++e)
    ad[e] = rep8 ^ (((unsigned)P.xm[e]) << 3);   // xm<<3 folds to SALU (uniform)

  f2 a[NE];
  #pragma unroll
  for (int e = 0; e < NE; ++e) a[e] = *(const f2*)((const char*)st + ad[e]);

  #pragma unroll
  for (int i = 0; i < NW_; ++i) {
    const float ci = c[i], si = sa[i];
    #pragma unroll
    for (int e = 0; e < NE; ++e) {
      if (!(e & (1 << i))) {
        f2 xe = a[e], ye = a[e | (1 << i)];
        a[e]            = ci * xe - si * ye;   // v_pk_fma candidates
        a[e | (1 << i)] = si * xe + ci * ye;
      }
    }
  }
  #pragma unroll
  for (int e = 0; e < NE; ++e) *(f2*)((char*)st + ad[e]) = a[e];
}

template <bool USE_WS>
__global__ __launch_bounds__(TPB, 1) void qsim_kernel(
    const float* __restrict__ inp, const float* __restrict__ theta,
    float* __restrict__ out, const float2* __restrict__ tt,
    const float4* __restrict__ albe, int use_albe, SimConsts C) {
  __shared__ f2 st[NSTATE];   // 128 KiB
  const int s = blockIdx.x;
  const int t = threadIdx.x;

  // ---- init: product state after RX(inp) then RY(theta layer 0)
  f2 A[NQ], B[NQ];
  if constexpr (USE_WS) {
    if (use_albe) {
      #pragma unroll
      for (int w = 0; w < NQ; ++w) {
        float4 v = albe[s * NQ + w];       // uniform -> s_load_dwordx4
        A[w].x = v.x; A[w].y = v.y;
        B[w].x = v.z; B[w].y = v.w;
      }
    } else {
      #pragma unroll
      for (int w = 0; w < NQ; ++w) {
        float sx, cx; __sincosf(0.5f * inp[s * NQ + w], &sx, &cx);
        float2 tv = tt[w];                 // layer-0 theta trig
        A[w].x = tv.x * cx; A[w].y = tv.y * sx;
        B[w].x = tv.y * cx; B[w].y = -tv.x * sx;
      }
    }
  } else {
    #pragma unroll
    for (int w = 0; w < NQ; ++w) {
      float sx, cx; __sincosf(0.5f * inp[s * NQ + w], &sx, &cx);
      float stt, ctt; __sincosf(0.5f * theta[w], &stt, &ctt);
      A[w].x = ctt * cx; A[w].y = stt * sx;
      B[w].x = stt * cx; B[w].y = -ctt * sx;
    }
  }

  f2 rhi; rhi.x = 1.f; rhi.y = 0.f;
  #pragma unroll
  for (int b = 0; b < 9; ++b) {            // p bit b <- t bit b, wire 13-b
    const int w = 13 - b;
    f2 f = ((t >> b) & 1) ? B[w] : A[w];
    rhi = cmulv(rhi, f);
  }
  f2 a[32];
  a[0] = rhi;
  #pragma unroll
  for (int k = 0; k < 5; ++k) {            // e bit k <-> p bit 9+k <-> wire 4-k
    const int w = 4 - k;
    const int sz = 1 << k;
    #pragma unroll
    for (int j = 0; j < 16; ++j) {
      if (j < sz) {
        f2 v = a[j];
        a[j]      = cmulv(v, A[w]);
        a[j + sz] = cmulv(v, B[w]);
      }
    }
  }
  #pragma unroll
  for (int e = 0; e < 32; ++e) st[(e << 9) | t] = a[e];
  __syncthreads();

  // ---- layers 1..7: RY only (CNOT rings absorbed into the L/K linear maps)
  #pragma unroll 1
  for (int d = 1; d <= 7; ++d) {
    const float* th = theta + d * NQ;
    const float2* ttd = USE_WS ? (tt + d * NQ) : nullptr;
    ry_group<5, USE_WS>(st, C.pass[d - 1][0], th, ttd, 0, (unsigned)t);
    __syncthreads();
    ry_group<5, USE_WS>(st, C.pass[d - 1][1], th, ttd, 5, (unsigned)t);
    __syncthreads();
    ry_group<4, USE_WS>(st, C.pass[d - 1][2], th, ttd, 10, (unsigned)t);
    ry_group<4, USE_WS>(st, C.pass[d - 1][2], th, ttd, 10, (unsigned)(t + TPB));
    __syncthreads();
  }

  // ---- measurement: <Z_w> via 5-bit Walsh-Hadamard over the e-axis
  float pv[32];
  #pragma unroll
  for (int e = 0; e < 32; ++e) {
    f2 v = st[(e << 9) | t];
    pv[e] = v.x * v.x + v.y * v.y;
  }
  __syncthreads();
  #pragma unroll
  for (int s5 = 0; s5 < 5; ++s5) {
    const int step = 1 << s5;
    #pragma unroll
    for (int e = 0; e < 32; ++e) {
      if (!(e & step)) {
        float x = pv[e], y = pv[e | step];
        pv[e] = x + y; pv[e | step] = x - y;
      }
    }
  }
  float* stf = (float*)st;
  #pragma unroll
  for (int e = 0; e < 32; ++e) stf[(e << 9) | t] = pv[e];   // [lam][t] layout
  __syncthreads();

  float acc[NQ];
  #pragma unroll
  for (int w = 0; w < NQ; ++w) {
    const unsigned zr = (unsigned)C.zrow[w];
    float v = stf[(zr & 0x3E00u) | (unsigned)t];   // WHT at frequency zr>>9
    acc[w] = (__popc(zr & (unsigned)t) & 1) ? -v : v;
  }
  #pragma unroll
  for (int w = 0; w < NQ; ++w) {
    #pragma unroll
    for (int off = 32; off > 0; off >>= 1)
      acc[w] += __shfl_xor(acc[w], off, 64);
  }
  __syncthreads();
  const int lane = t & 63, wid = t >> 6;
  if (lane == 0) {
    #pragma unroll
    for (int w = 0; w < NQ; ++w) stf[wid * NQ + w] = acc[w];
  }
  __syncthreads();
  if (t < NQ) {
    float tot = 0.f;
    #pragma unroll
    for (int k = 0; k < 8; ++k) tot += stf[k * NQ + t];
    out[s * NQ + t] = tot;
  }
}

// ---------- prep: precise trig tables into workspace ----------
__global__ void prep_kernel(const float* __restrict__ inp,
                            const float* __restrict__ theta,
                            float2* __restrict__ tt, float4* __restrict__ albe,
                            int nAlbe) {
  const int i = blockIdx.x * 256 + threadIdx.x;
  if (i < DEPTH * NQ) {
    float ss, cc; sincosf(0.5f * theta[i], &ss, &cc);
    tt[i] = make_float2(cc, ss);
  }
  if (albe != nullptr && i < nAlbe) {
    const int w = i % NQ;
    float sx, cx; sincosf(0.5f * inp[i], &sx, &cx);
    float stt, ctt; sincosf(0.5f * theta[w], &stt, &ctt);
    albe[i] = make_float4(ctt * cx, stt * sx, stt * cx, -ctt * sx);
  }
}

// ---------- host: GF(2) linear algebra for the CNOT-ring permutation ----------
static inline unsigned ffwd(unsigned x) {
  unsigned t = x;
  t ^= t >> 1; t ^= t >> 2; t ^= t >> 4; t ^= t >> 8;
  unsigned y = t & 0x1FFFu;
  y |= (((t >> 13) ^ t) & 1u) << 13;
  return y;
}
static inline unsigned finv(unsigned y) {
  unsigned x = 0;
  for (int j = 0; j <= 11; ++j) x |= (((y >> j) ^ (y >> (j + 1))) & 1u) << j;
  x |= (((y >> 12) ^ (y >> 13) ^ y) & 1u) << 12;
  x |= (((y >> 13) ^ y) & 1u) << 13;
  return x;
}

extern "C" void kernel_launch(void* const* d_in, const int* in_sizes, int n_in,
                              void* d_out, int out_size, void* d_ws, size_t ws_size,
                              hipStream_t stream) {
  const float* inp = (const float*)d_in[0];
  const float* theta = (const float*)d_in[1];
  float* out = (float*)d_out;
  const int batch = in_sizes[0] / NQ;

  SimConsts C;
  u16 Lc[NQ], Kc[NQ];   // columns of L = F^d and K = L^-1
  for (int j = 0; j < NQ; ++j) { Lc[j] = (u16)(1u << j); Kc[j] = (u16)(1u << j); }
  for (int d = 1; d <= 8; ++d) {
    u16 nL[NQ], nK[NQ];
    for (int j = 0; j < NQ; ++j) nL[j] = (u16)ffwd((unsigned)Lc[j]);
    for (int j = 0; j < NQ; ++j) {
      unsigned fj = finv(1u << j);
      unsigned v = 0;
      for (int b = 0; b < NQ; ++b) if ((fj >> b) & 1u) v ^= Kc[b];
      nK[j] = (u16)v;
    }
    for (int j = 0; j < NQ; ++j) { Lc[j] = nL[j]; Kc[j] = nK[j]; }

    if (d <= 7) {
      for (int pg = 0; pg < 3; ++pg) {
        const int wbase = pg * 5;
        const int nw = (pg == 2) ? 4 : 5;
        const int NB = 14 - nw;
        PassK& P = C.pass[d - 1][pg];
        u16 mk[5] = {0, 0, 0, 0, 0};
        for (int i = 0; i < 5; ++i) P.srow[i] = 0;

        // incremental GF(2) independence structure: red[b] has leading bit b
        unsigned red[14] = {0};
        auto tryAdd = [&](unsigned x) -> bool {
          while (x) {
            int h = 31 - __builtin_clz(x);
            if (!red[h]) { red[h] = x; return true; }
            x ^= red[h];
          }
          return false;
        };

        for (int i = 0; i < nw; ++i) {
          const int bit = 13 - (wbase + i);
          mk[i] = Kc[bit];                       // pair mask = column of K
          tryAdd((unsigned)mk[i]);               // masks are independent
          unsigned r = 0;                        // row of L at 'bit'
          for (int j = 0; j < NQ; ++j) r |= ((unsigned)(Lc[j] >> bit) & 1u) << j;
          P.srow[i] = (u16)r;
        }

        // conflict-free complement basis:
        //  scol[0..3]: low nibble == e_i  (lane bits 0..3 -> idx bits 0..3)
        //  scol[4.. ]: low nibble == 0
        for (int i = 0; i < 4; ++i) {
          for (unsigned h = 0; h < 1024u; ++h) {
            unsigned cand = (1u << i) ^ (h << 4);
            if (tryAdd(cand)) { P.scol[i] = (u16)cand; break; }
          }
        }
        for (int i = 4; i < NB; ++i) {
          for (unsigned h = 1; h < 1024u; ++h) {
            unsigned cand = h << 4;
            if (tryAdd(cand)) { P.scol[i] = (u16)cand; break; }
          }
        }
        for (int i = NB; i < 10; ++i) P.scol[i] = 0;

        const int ne = 1 << nw;
        for (int e = 0; e < 32; ++e) {
          unsigned v = 0;
          if (e < ne)
            for (int i = 0; i < nw; ++i)
              if ((e >> i) & 1) v ^= mk[i];
          P.xm[e] = (u16)v;
        }
      }
    } else {
      for (int w = 0; w < NQ; ++w) {
        const int bit = 13 - w;
        unsigned r = 0;
        for (int j = 0; j < NQ; ++j) r |= ((unsigned)(Lc[j] >> bit) & 1u) << j;
        C.zrow[w] = (u16)r;
      }
    }
  }

  // workspace layout: [0,896) theta trig (float2), [1024, 1024+batch*NQ*16) albe (float4)
  const size_t needT = (size_t)(DEPTH * NQ) * sizeof(float2);
  const size_t needA = 1024 + (size_t)batch * NQ * sizeof(float4);
  const bool useT = ws_size >= 1024 && needT <= 1024;
  const bool useA = useT && ws_size >= needA;
  float2* tt = (float2*)d_ws;
  float4* albe = (float4*)((char*)d_ws + 1024);

  if (useT) {
    const int nAlbe = useA ? batch * NQ : 0;
    const int nwork = useA ? nAlbe : DEPTH * NQ;
    prep_kernel<<<(nwork + 255) / 256, 256, 0, stream>>>(
        inp, theta, tt, useA ? albe : nullptr, nAlbe);
    qsim_kernel<true><<<batch, TPB, 0, stream>>>(inp, theta, out, tt, albe,
                                                 useA ? 1 : 0, C);
  } else {
    qsim_kernel<false><<<batch, TPB, 0, stream>>>(inp, theta, out, nullptr,
                                                  nullptr, 0, C);
  }
}

// Round 4
// 224.961 us; speedup vs baseline: 1.8425x; 1.0839x over previous
//
#include <hip/hip_runtime.h>

typedef unsigned short u16;
typedef float f2 __attribute__((ext_vector_type(2)));

#define NQ 14
#define NSTATE (1 << NQ)   // 16384
#define DEPTH 8
#define TPB 512

// ---------- host-side constants passed by value ----------
struct PassK7 {
  u16 cm[2];       // cross-wire pair masks (lane^1, lane^2)
  u16 srow[7];     // rows of L: sign parity per wire (0..4 in-reg, 5..6 cross)
  u16 scol[7];     // complement basis for coset enumeration (grp bits)
  u16 xm[32];      // XOR combos of the 5 in-register pair masks
};

struct SimConsts {
  PassK7 pass[7][2];  // layers 1..7 x {wires 0-6, wires 7-13}
  u16 zrow[14];       // rows of L_8 for <Z_w> sign
  u16 zfreq[14];      // WHT frequency per wire in layer-7/pass-2 mask basis
};

// ---------- device ----------
__device__ __forceinline__ f2 cmulv(f2 a, f2 b) {
  f2 r;
  r.x = a.x * b.x - a.y * b.y;
  r.y = a.x * b.y + a.y * b.x;
  return r;
}

template <int CTRL>
__device__ __forceinline__ f2 dpp_f2(f2 v) {
  f2 r;
  r.x = __int_as_float(
      __builtin_amdgcn_mov_dpp(__float_as_int(v.x), CTRL, 0xf, 0xf, true));
  r.y = __int_as_float(
      __builtin_amdgcn_mov_dpp(__float_as_int(v.y), CTRL, 0xf, 0xf, true));
  return r;
}

// 7-wire RY pass: 5 wires in-register + 2 wires via DPP quad_perm.
// If !WRITE, leaves results in a[] and repx in *repx_out (caller finishes).
template <bool USE_WS, bool WRITE>
__device__ __forceinline__ void ry7(f2* st, const PassK7& P, const float* th,
                                    const float2* ttd, int wbase, int t,
                                    f2* a, unsigned* repx_out) {
  const unsigned grp = ((unsigned)t) >> 2;
  unsigned rep = 0;
  #pragma unroll
  for (int b = 0; b < 7; ++b)
    rep ^= ((grp >> b) & 1u) ? (unsigned)P.scol[b] : 0u;
  unsigned repx = rep ^ ((t & 1) ? (unsigned)P.cm[0] : 0u)
                      ^ ((t & 2) ? (unsigned)P.cm[1] : 0u);
  *repx_out = repx;

  float c[7], ss[7];
  #pragma unroll
  for (int i = 0; i < 7; ++i) {
    if constexpr (USE_WS) {
      float2 tv = ttd[wbase + i];      // uniform -> s_load
      c[i] = tv.x; ss[i] = tv.y;
    } else {
      __sincosf(0.5f * th[wbase + i], &ss[i], &c[i]);
    }
  }
  float sa[5];
  #pragma unroll
  for (int i = 0; i < 5; ++i)
    sa[i] = (__popc((unsigned)P.srow[i] & rep) & 1) ? -ss[i] : ss[i];
  const float sg5 =
      ((__popc((unsigned)P.srow[5] & rep) ^ t) & 1) ? ss[5] : -ss[5];
  const float sg6 =
      ((__popc((unsigned)P.srow[6] & rep) ^ (t >> 1)) & 1) ? ss[6] : -ss[6];

  const unsigned base = repx << 3;
  unsigned ad[32];
  #pragma unroll
  for (int e = 0; e < 32; ++e)
    ad[e] = base ^ (((unsigned)P.xm[e]) << 3);   // xm<<3 uniform (SGPR)

  #pragma unroll
  for (int e = 0; e < 32; ++e) a[e] = *(const f2*)((const char*)st + ad[e]);

  // cross wire 5: partner = lane^1 (quad_perm [1,0,3,2])
  {
    const float c5 = c[5];
    #pragma unroll
    for (int e = 0; e < 32; ++e) {
      f2 p = dpp_f2<0xB1>(a[e]);
      a[e] = c5 * a[e] + sg5 * p;
    }
  }
  // 5 in-register wires
  #pragma unroll
  for (int i = 0; i < 5; ++i) {
    const float ci = c[i], si = sa[i];
    #pragma unroll
    for (int e = 0; e < 32; ++e) {
      if (!(e & (1 << i))) {
        f2 xe = a[e], ye = a[e | (1 << i)];
        a[e]            = ci * xe - si * ye;
        a[e | (1 << i)] = si * xe + ci * ye;
      }
    }
  }
  // cross wire 6: partner = lane^2 (quad_perm [2,3,0,1])
  {
    const float c6 = c[6];
    #pragma unroll
    for (int e = 0; e < 32; ++e) {
      f2 p = dpp_f2<0x4E>(a[e]);
      a[e] = c6 * a[e] + sg6 * p;
    }
  }

  if constexpr (WRITE) {
    #pragma unroll
    for (int e = 0; e < 32; ++e) *(f2*)((char*)st + ad[e]) = a[e];
  }
}

template <bool USE_WS>
__global__ __launch_bounds__(TPB, 1) void qsim_kernel(
    const float* __restrict__ inp, const float* __restrict__ theta,
    float* __restrict__ out, const float2* __restrict__ tt,
    const float4* __restrict__ albe, int use_albe, SimConsts C) {
  __shared__ f2 st[NSTATE];   // 128 KiB
  const int s = blockIdx.x;
  const int t = threadIdx.x;

  // ---- init: product state after RX(inp) then RY(theta layer 0)
  f2 A[NQ], B[NQ];
  if constexpr (USE_WS) {
    if (use_albe) {
      #pragma unroll
      for (int w = 0; w < NQ; ++w) {
        float4 v = albe[s * NQ + w];       // uniform -> s_load_dwordx4
        A[w].x = v.x; A[w].y = v.y;
        B[w].x = v.z; B[w].y = v.w;
      }
    } else {
      #pragma unroll
      for (int w = 0; w < NQ; ++w) {
        float sx, cx; __sincosf(0.5f * inp[s * NQ + w], &sx, &cx);
        float2 tv = tt[w];
        A[w].x = tv.x * cx; A[w].y = tv.y * sx;
        B[w].x = tv.y * cx; B[w].y = -tv.x * sx;
      }
    }
  } else {
    #pragma unroll
    for (int w = 0; w < NQ; ++w) {
      float sx, cx; __sincosf(0.5f * inp[s * NQ + w], &sx, &cx);
      float stt, ctt; __sincosf(0.5f * theta[w], &stt, &ctt);
      A[w].x = ctt * cx; A[w].y = stt * sx;
      B[w].x = stt * cx; B[w].y = -ctt * sx;
    }
  }

  f2 a[32];
  {
    f2 rhi; rhi.x = 1.f; rhi.y = 0.f;
    #pragma unroll
    for (int b = 0; b < 9; ++b) {          // p bit b <- t bit b, wire 13-b
      const int w = 13 - b;
      f2 f = ((t >> b) & 1) ? B[w] : A[w];
      rhi = cmulv(rhi, f);
    }
    a[0] = rhi;
    #pragma unroll
    for (int k = 0; k < 5; ++k) {          // e bit k <-> p bit 9+k <-> wire 4-k
      const int w = 4 - k;
      const int sz = 1 << k;
      #pragma unroll
      for (int j = 0; j < 16; ++j) {
        if (j < sz) {
          f2 v = a[j];
          a[j]      = cmulv(v, A[w]);
          a[j + sz] = cmulv(v, B[w]);
        }
      }
    }
    #pragma unroll
    for (int e = 0; e < 32; ++e) st[(e << 9) | t] = a[e];
  }
  __syncthreads();

  // ---- layers 1..7, two 7-wire passes each (CNOT rings in the linear maps)
  unsigned repx;
  #pragma unroll 1
  for (int d = 1; d <= 6; ++d) {
    const float* th = theta + d * NQ;
    const float2* ttd = USE_WS ? (tt + d * NQ) : nullptr;
    ry7<USE_WS, true>(st, C.pass[d - 1][0], th, ttd, 0, t, a, &repx);
    __syncthreads();
    ry7<USE_WS, true>(st, C.pass[d - 1][1], th, ttd, 7, t, a, &repx);
    __syncthreads();
  }
  {
    const float* th = theta + 7 * NQ;
    const float2* ttd = USE_WS ? (tt + 7 * NQ) : nullptr;
    ry7<USE_WS, true>(st, C.pass[6][0], th, ttd, 0, t, a, &repx);
    __syncthreads();
    // last pass: keep results in registers, fuse measurement
    ry7<USE_WS, false>(st, C.pass[6][1], th, ttd, 7, t, a, &repx);
  }
  __syncthreads();   // all reads of the final pass done before st is reused

  // ---- measurement: per-thread |amp|^2, 5-bit WHT in mask basis
  float pv[32];
  #pragma unroll
  for (int e = 0; e < 32; ++e) pv[e] = a[e].x * a[e].x + a[e].y * a[e].y;
  #pragma unroll
  for (int s5 = 0; s5 < 5; ++s5) {
    const int step = 1 << s5;
    #pragma unroll
    for (int e = 0; e < 32; ++e) {
      if (!(e & step)) {
        float x = pv[e], y = pv[e | step];
        pv[e] = x + y; pv[e | step] = x - y;
      }
    }
  }
  float* stf = (float*)st;
  #pragma unroll
  for (int e = 0; e < 32; ++e) stf[(e << 9) | t] = pv[e];
  __syncthreads();

  float acc[NQ];
  #pragma unroll
  for (int w = 0; w < NQ; ++w) {
    const unsigned zf = (unsigned)C.zfreq[w];
    float v = stf[(zf << 9) | (unsigned)t];
    acc[w] = (__popc((unsigned)C.zrow[w] & repx) & 1) ? -v : v;
  }
  #pragma unroll
  for (int w = 0; w < NQ; ++w) {
    #pragma unroll
    for (int off = 32; off > 0; off >>= 1)
      acc[w] += __shfl_xor(acc[w], off, 64);
  }
  __syncthreads();
  const int lane = t & 63, wid = t >> 6;
  if (lane == 0) {
    #pragma unroll
    for (int w = 0; w < NQ; ++w) stf[wid * NQ + w] = acc[w];
  }
  __syncthreads();
  if (t < NQ) {
    float tot = 0.f;
    #pragma unroll
    for (int k = 0; k < 8; ++k) tot += stf[k * NQ + t];
    out[s * NQ + t] = tot;
  }
}

// ---------- prep: precise trig tables into workspace ----------
__global__ void prep_kernel(const float* __restrict__ inp,
                            const float* __restrict__ theta,
                            float2* __restrict__ tt, float4* __restrict__ albe,
                            int nAlbe) {
  const int i = blockIdx.x * 256 + threadIdx.x;
  if (i < DEPTH * NQ) {
    float ss, cc; sincosf(0.5f * theta[i], &ss, &cc);
    tt[i] = make_float2(cc, ss);
  }
  if (albe != nullptr && i < nAlbe) {
    const int w = i % NQ;
    float sx, cx; sincosf(0.5f * inp[i], &sx, &cx);
    float stt, ctt; sincosf(0.5f * theta[w], &stt, &ctt);
    albe[i] = make_float4(ctt * cx, stt * sx, stt * cx, -ctt * sx);
  }
}

// ---------- host: GF(2) linear algebra for the CNOT-ring permutation ----------
static inline unsigned ffwd(unsigned x) {
  unsigned t = x;
  t ^= t >> 1; t ^= t >> 2; t ^= t >> 4; t ^= t >> 8;
  unsigned y = t & 0x1FFFu;
  y |= (((t >> 13) ^ t) & 1u) << 13;
  return y;
}
static inline unsigned finv(unsigned y) {
  unsigned x = 0;
  for (int j = 0; j <= 11; ++j) x |= (((y >> j) ^ (y >> (j + 1))) & 1u) << j;
  x |= (((y >> 12) ^ (y >> 13) ^ y) & 1u) << 12;
  x |= (((y >> 13) ^ y) & 1u) << 13;
  return x;
}

extern "C" void kernel_launch(void* const* d_in, const int* in_sizes, int n_in,
                              void* d_out, int out_size, void* d_ws, size_t ws_size,
                              hipStream_t stream) {
  const float* inp = (const float*)d_in[0];
  const float* theta = (const float*)d_in[1];
  float* out = (float*)d_out;
  const int batch = in_sizes[0] / NQ;

  SimConsts C;
  u16 Lc[NQ], Kc[NQ];   // columns of L = F^d and K = L^-1
  u16 mk2last[5] = {0, 0, 0, 0, 0};   // in-reg masks of layer-7 pass-2
  for (int j = 0; j < NQ; ++j) { Lc[j] = (u16)(1u << j); Kc[j] = (u16)(1u << j); }
  for (int d = 1; d <= 8; ++d) {
    u16 nL[NQ], nK[NQ];
    for (int j = 0; j < NQ; ++j) nL[j] = (u16)ffwd((unsigned)Lc[j]);
    for (int j = 0; j < NQ; ++j) {
      unsigned fj = finv(1u << j);
      unsigned v = 0;
      for (int b = 0; b < NQ; ++b) if ((fj >> b) & 1u) v ^= Kc[b];
      nK[j] = (u16)v;
    }
    for (int j = 0; j < NQ; ++j) { Lc[j] = nL[j]; Kc[j] = nK[j]; }

    if (d <= 7) {
      for (int pg = 0; pg < 2; ++pg) {
        const int wbase = pg * 7;
        PassK7& P = C.pass[d - 1][pg];

        // incremental GF(2) independence: red[b] has leading bit b
        unsigned red[14] = {0};
        auto tryAdd = [&](unsigned x) -> bool {
          while (x) {
            int h = 31 - __builtin_clz(x);
            if (!red[h]) { red[h] = x; return true; }
            x ^= red[h];
          }
          return false;
        };

        u16 mk[5];
        for (int i = 0; i < 7; ++i) {
          const int bit = 13 - (wbase + i);
          unsigned m = Kc[bit];              // pair mask = column of K
          tryAdd(m);                          // K invertible -> independent
          if (i < 5) mk[i] = (u16)m; else P.cm[i - 5] = (u16)m;
          unsigned r = 0;                     // row of L at 'bit'
          for (int j = 0; j < NQ; ++j) r |= ((unsigned)(Lc[j] >> bit) & 1u) << j;
          P.srow[i] = (u16)r;
        }
        if (d == 7 && pg == 1)
          for (int i = 0; i < 5; ++i) mk2last[i] = mk[i];

        // complement basis: scol[0..3] low4 == e_i (bank-spread), rest low4 == 0
        for (int i = 0; i < 4; ++i) {
          bool ok = false;
          for (unsigned h = 0; h < 1024u && !ok; ++h)
            if (tryAdd((1u << i) ^ (h << 4))) { P.scol[i] = (u16)((1u << i) ^ (h << 4)); ok = true; }
          for (unsigned cand = 1; cand < 16384u && !ok; ++cand)
            if (tryAdd(cand)) { P.scol[i] = (u16)cand; ok = true; }
        }
        for (int i = 4; i < 7; ++i) {
          bool ok = false;
          for (unsigned h = 1; h < 1024u && !ok; ++h)
            if (tryAdd(h << 4)) { P.scol[i] = (u16)(h << 4); ok = true; }
          for (unsigned cand = 1; cand < 16384u && !ok; ++cand)
            if (tryAdd(cand)) { P.scol[i] = (u16)cand; ok = true; }
        }

        for (int e = 0; e < 32; ++e) {
          unsigned v = 0;
          for (int i = 0; i < 5; ++i)
            if ((e >> i) & 1) v ^= (unsigned)mk[i];
          P.xm[e] = (u16)v;
        }
      }
    } else {
      for (int w = 0; w < NQ; ++w) {
        const int bit = 13 - w;
        unsigned r = 0;
        for (int j = 0; j < NQ; ++j) r |= ((unsigned)(Lc[j] >> bit) & 1u) << j;
        C.zrow[w] = (u16)r;
        unsigned zf = 0;
        for (int i = 0; i < 5; ++i)
          zf |= (unsigned)(__builtin_popcount(r & (unsigned)mk2last[i]) & 1) << i;
        C.zfreq[w] = (u16)zf;
      }
    }
  }

  // workspace: [0,896) theta trig (float2); [1024, ...) albe (float4)
  const size_t needT = (size_t)(DEPTH * NQ) * sizeof(float2);
  const size_t needA = 1024 + (size_t)batch * NQ * sizeof(float4);
  const bool useT = ws_size >= 1024 && needT <= 1024;
  const bool useA = useT && ws_size >= needA;
  float2* tt = (float2*)d_ws;
  float4* albe = (float4*)((char*)d_ws + 1024);

  if (useT) {
    const int nAlbe = useA ? batch * NQ : 0;
    const int nwork = useA ? nAlbe : DEPTH * NQ;
    prep_kernel<<<(nwork + 255) / 256, 256, 0, stream>>>(
        inp, theta, tt, useA ? albe : nullptr, nAlbe);
    qsim_kernel<true><<<batch, TPB, 0, stream>>>(inp, theta, out, tt, albe,
                                                 useA ? 1 : 0, C);
  } else {
    qsim_kernel<false><<<batch, TPB, 0, stream>>>(inp, theta, out, nullptr,
                                                  nullptr, 0, C);
  }
}